// Round 1
// baseline (870.594 us; speedup 1.0000x reference)
//
#include <hip/hip_runtime.h>

// FootprintExtruder: extrude [H,W] height/seg maps into [Z,H,W] int32 volume.
// Constants from the reference:
#define L1_HEIGHT 0      // z < 0 never true -> branch dead
#define ROOF_HEIGHT 1
#define ROOF_ID_OFFSET 1
#define FP_ID_MIN 100
#define FP_ID_MAX 5000
#define MAX_HEIGHT 384
#define HH 768
#define WW 768
#define HW (HH * WW)     // 589824, divisible by 1024

// z-planes per block: each thread loads hf/seg ONCE, then streams ZPB stores.
// 384/ZPB = 8 z-chunks -> grid (576, 8) = 4608 blocks (18 blocks/CU) -- enough
// waves to saturate HBM while amortizing kernarg/addr/load overhead 48x.
#define ZPB 48
#define ZBLOCKS (MAX_HEIGHT / ZPB)

typedef int vint4 __attribute__((ext_vector_type(4)));

__device__ __forceinline__ int voxel(int z, int hf, int seg, int roofv) {
    // z < L1_HEIGHT(=0) impossible. Inside z<hf, "z >= hf-ROOF_HEIGHT" <=> z == hf-1.
    return (z < hf) ? ((z == hf - 1) ? roofv : seg) : 0;
}

// grid = (HW/1024, ZBLOCKS); block = 256; each thread: one int4 column chunk
// of 48 z-planes. Loads happen once; loop body is 4 VALU/elem + 1 nt store.
__global__ __launch_bounds__(256) void extrude_kernel(
        const int* __restrict__ hf_map, const int* __restrict__ seg_map,
        int* __restrict__ out) {
    const int p  = (blockIdx.x * 256 + threadIdx.x) * 4;  // plane offset
    const int z0 = blockIdx.y * ZPB;

    const vint4 hf4 = *(const vint4*)(hf_map  + p);
    const vint4 sg4 = *(const vint4*)(seg_map + p);

    // Value at the roof voxel (z == hf-1): footprint ids get +ROOF_ID_OFFSET.
    vint4 rf4;
    rf4.x = sg4.x + (((sg4.x >= FP_ID_MIN) & (sg4.x < FP_ID_MAX)) ? ROOF_ID_OFFSET : 0);
    rf4.y = sg4.y + (((sg4.y >= FP_ID_MIN) & (sg4.y < FP_ID_MAX)) ? ROOF_ID_OFFSET : 0);
    rf4.z = sg4.z + (((sg4.z >= FP_ID_MIN) & (sg4.z < FP_ID_MAX)) ? ROOF_ID_OFFSET : 0);
    rf4.w = sg4.w + (((sg4.w >= FP_ID_MIN) & (sg4.w < FP_ID_MAX)) ? ROOF_ID_OFFSET : 0);

    int* outp = out + (size_t)z0 * HW + p;

    #pragma unroll 4
    for (int z = z0; z < z0 + ZPB; ++z) {
        vint4 o;
        o.x = voxel(z, hf4.x, sg4.x, rf4.x);
        o.y = voxel(z, hf4.y, sg4.y, rf4.y);
        o.z = voxel(z, hf4.z, sg4.z, rf4.z);
        o.w = voxel(z, hf4.w, sg4.w, rf4.w);
        // 906 MB write-only stream: nontemporal to avoid L2 pollution.
        __builtin_nontemporal_store(o, (vint4*)outp);
        outp += HW;
    }
}

extern "C" void kernel_launch(void* const* d_in, const int* in_sizes, int n_in,
                              void* d_out, int out_size, void* d_ws, size_t ws_size,
                              hipStream_t stream) {
    const int* hf  = (const int*)d_in[0];   // height_field [1,768,768] int32
    const int* seg = (const int*)d_in[1];   // seg_map      [1,768,768] int32
    int* out = (int*)d_out;                 // [1,384,768,768] int32

    dim3 grid(HW / 1024, ZBLOCKS);          // 576 x 8 blocks
    extrude_kernel<<<grid, 256, 0, stream>>>(hf, seg, out);
}